// Round 5
// baseline (1361.533 us; speedup 1.0000x reference)
//
#include <hip/hip_runtime.h>
#include <hip/hip_cooperative_groups.h>
#include <hip/hip_bf16.h>
#include <math.h>

namespace cg = cooperative_groups;

// MoE MLP: B=4, S=2048, H=1024, D_FF=4096, E=8, top-2.
// Round 7:
//  - ONE cooperative prep kernel (cvt weights + router + setup + scatter +
//    gather, grid.sync between phases) -> 10 graph nodes down to 4.
//  - FC2: 2 fat phases per K-tile (16 MFMA/phase), counted vmcnt(4)/(2),
//    half the barriers of R4's 4-thin-phase version.
//  - FC1: R4 gemm4p verbatim (verified 243 us).

#define TT  8192    // tokens = B*S
#define HD  1024    // hidden
#define DFF 4096    // ffn dim
#define NE  8       // experts
#define ROWCAP 18432   // gathered rows, per-expert pad to 256
#define MAXT 72        // sum ceil(counts[e]/256) <= 72

typedef __attribute__((ext_vector_type(8))) short short8;
typedef __attribute__((ext_vector_type(4))) float f32x4;

// fp32 -> bf16 round-to-nearest-even (finite inputs)
static __device__ __forceinline__ unsigned short f2bf(float f) {
    unsigned int u = __float_as_uint(f);
    unsigned int r = (u + 0x7fffu + ((u >> 16) & 1u)) >> 16;
    return (unsigned short)r;
}

static __device__ __forceinline__ float bf2f(unsigned short u) {
    return __uint_as_float((unsigned int)u << 16);
}

// gelu tanh-form via sigmoid: v * sigmoid(1.5957691*(v + 0.044715 v^3)).
static __device__ __forceinline__ float gelu_fast(float v) {
    const float s = v * (1.5957691f + 0.07135481f * v * v);
    return v / (1.f + __expf(-s));
}

// async global->LDS, 16 bytes per lane. LDS dest = wave-uniform base + lane*16.
static __device__ __forceinline__ void gload_lds16(const void* gp, void* lp) {
    __builtin_amdgcn_global_load_lds(
        (__attribute__((address_space(1))) void*)(void*)gp,
        (__attribute__((address_space(3))) void*)lp,
        16, 0, 0);
}

#define BARM                                        \
    __builtin_amdgcn_s_barrier();                   \
    asm volatile("" ::: "memory");                  \
    __builtin_amdgcn_sched_barrier(0)
#define LGKM0                                       \
    asm volatile("s_waitcnt lgkmcnt(0)" ::: "memory"); \
    __builtin_amdgcn_sched_barrier(0)
#define PRIO1 __builtin_amdgcn_s_setprio(1)
#define PRIO0 __builtin_amdgcn_s_setprio(0)
#define VMC(NN) asm volatile("s_waitcnt vmcnt(%0)" ::"n"(NN) : "memory")

// ------------------------------------------------------------- cooperative prep
// Phase A: weights->bf16 (+zero counts). B: router. C: init rows + tile map.
// D: scatter. E: gather. grid.sync() between phases. 512 blocks x 256 thr,
// 32 KB LDS, <=256 VGPR -> >=2 blocks/CU co-resident (512 <= 2*256).
__global__ __launch_bounds__(256, 2) void prep_kernel(
    const float* __restrict__ x, const float* __restrict__ wr,
    const float* __restrict__ w1, const float* __restrict__ w2,
    unsigned short* __restrict__ Wb1, unsigned short* __restrict__ Wb2,
    int* __restrict__ tokE, float* __restrict__ tokW,
    int* __restrict__ counts, int* __restrict__ cursor,
    int* __restrict__ tE, int* __restrict__ tR,
    int* __restrict__ rowTok, int* __restrict__ posOf,
    unsigned short* __restrict__ Xg, int doW2) {
    cg::grid_group grid = cg::this_grid();
    const int tid = threadIdx.x;
    const long gt = (long)blockIdx.x * 256 + tid;
    const long gsz = (long)gridDim.x * 256;

    // ---- phase A: weight conversion + zero counts
    if (gt < NE) counts[gt] = 0;
    const long n4 = (long)NE * DFF * HD / 4;
    for (long i = gt; i < n4; i += gsz) {
        float4 v = ((const float4*)w1)[i];
        ushort4 o;
        o.x = f2bf(v.x); o.y = f2bf(v.y); o.z = f2bf(v.z); o.w = f2bf(v.w);
        ((ushort4*)Wb1)[i] = o;
        if (doW2) {
            float4 u = ((const float4*)w2)[i];
            ushort4 q;
            q.x = f2bf(u.x); q.y = f2bf(u.y); q.z = f2bf(u.z); q.w = f2bf(u.w);
            ((ushort4*)Wb2)[i] = q;
        }
    }
    __threadfence();
    grid.sync();

    // ---- phase B: router (x read once; wr in LDS; fp64 accumulation with the
    // verified summation order -> bit-identical top-k)
    __shared__ float wrs[NE * HD];  // 32 KB
#pragma unroll
    for (int i = 0; i < NE * HD / 4 / 256; ++i)
        ((float4*)wrs)[i * 256 + tid] = ((const float4*)wr)[i * 256 + tid];
    __syncthreads();
    const int lane = tid & 63;
    for (int token = blockIdx.x * 4 + (tid >> 6); token < TT; token += gridDim.x * 4) {
        const float* xp = x + (long)token * HD;
        double lg[NE];
#pragma unroll
        for (int e = 0; e < NE; ++e) lg[e] = 0.0;
        for (int i = lane; i < HD; i += 64) {
            const double xv = (double)xp[i];
#pragma unroll
            for (int e = 0; e < NE; ++e) lg[e] += xv * (double)wrs[e * HD + i];
        }
#pragma unroll
        for (int e = 0; e < NE; ++e) {
            double s = lg[e];
#pragma unroll
            for (int off = 32; off > 0; off >>= 1) s += __shfl_xor(s, off, 64);
            lg[e] = s;
        }
        if (lane == 0) {
            int i0 = 0; double v0 = lg[0];
#pragma unroll
            for (int e = 1; e < NE; ++e) if (lg[e] > v0) { v0 = lg[e]; i0 = e; }
            int i1 = -1; double v1 = -1e300;
#pragma unroll
            for (int e = 0; e < NE; ++e) if (e != i0 && lg[e] > v1) { v1 = lg[e]; i1 = e; }
            double p = exp(v1 - v0);  // v1 <= v0
            double d = 1.0 + p;
            tokE[token * 2] = i0;     tokW[token * 2] = (float)(1.0 / d);
            tokE[token * 2 + 1] = i1; tokW[token * 2 + 1] = (float)(p / d);
            atomicAdd(&counts[i0], 1);
            atomicAdd(&counts[i1], 1);
        }
    }
    __threadfence();
    grid.sync();

    // ---- phase C: init pad rows + tile map (single-thread scan, <200 iters)
    for (long i = gt; i < ROWCAP; i += gsz) rowTok[i] = 0;
    if (gt == 0) {
        int off = 0, t = 0;
        for (int e = 0; e < NE; ++e) {
            cursor[e] = off;
            const int padded = (counts[e] + 255) & ~255;
            for (int j = 0; j < padded / 256; ++j) {
                tE[t] = e; tR[t] = off + j * 256; ++t;
            }
            off += padded;
        }
        for (; t < MAXT; ++t) tE[t] = -1;
    }
    __threadfence();
    grid.sync();

    // ---- phase D: scatter (row->token and token->position maps)
    for (long t = gt; t < TT; t += gsz) {
#pragma unroll
        for (int j = 0; j < 2; ++j) {
            const int e = tokE[t * 2 + j];
            const int pos = atomicAdd(&cursor[e], 1);
            rowTok[pos] = (int)t;
            posOf[t * 2 + j] = pos;
        }
    }
    __threadfence();
    grid.sync();

    // ---- phase E: gather + cvt: Xg[row][:] = bf16(x[rowTok[row]][:])
    for (int row = blockIdx.x; row < ROWCAP; row += gridDim.x) {
        const int tok = rowTok[row];
        const float4 v = ((const float4*)(x + (long)tok * HD))[tid];
        ushort4 o;
        o.x = f2bf(v.x); o.y = f2bf(v.y); o.z = f2bf(v.z); o.w = f2bf(v.w);
        ((ushort4*)(Xg + (long)row * HD))[tid] = o;
    }
}

// fallback w2 cvt (only when workspace can't hold separate Wb2)
__global__ __launch_bounds__(256) void cvt_w_kernel(const float* __restrict__ s,
                                                    unsigned short* __restrict__ d,
                                                    long n4) {
    for (long i = (long)blockIdx.x * 256 + threadIdx.x; i < n4;
         i += (long)gridDim.x * 256) {
        float4 v = ((const float4*)s)[i];
        ushort4 o;
        o.x = f2bf(v.x); o.y = f2bf(v.y); o.z = f2bf(v.z); o.w = f2bf(v.w);
        ((ushort4*)d)[i] = o;
    }
}

// ------------------------------------------------------------- FC1 GEMM (R4, verified)
// BM=256, BK=64, 8 waves (2x4), double-buffered LDS, 4 phases/K-tile with
// counted vmcnt(VB) (never 0), XOR swizzle, setprio, XCD-bijective swizzle.
template <int EPI, int N, int K, int BN>
__global__ __launch_bounds__(512, 2) void gemm4p(
    const unsigned short* __restrict__ A,
    const unsigned short* __restrict__ W,
    const int* __restrict__ tE,
    const int* __restrict__ tR,
    unsigned short* __restrict__ Hout,
    const float* __restrict__ bias) {
    constexpr int BM = 256, BK = 64, NT = K / BK;
    constexpr int NREP = BN / 64;
    constexpr int NREP2 = NREP / 2;
    constexpr int NB = BN / 64;
    constexpr int NB2 = NB / 2;
    constexpr int HB = BN / 8;
    constexpr int LOG2HB = (BN == 256) ? 5 : 4;
    constexpr int VB = NB2 + 2;
    constexpr int AHALF = BM * BK;
    constexpr int HALF = (BM + BN) * BK;

    const int nwg = gridDim.x * gridDim.y;
    int bid = blockIdx.y * gridDim.x + blockIdx.x;
    bid = (bid & 7) * (nwg >> 3) + (bid >> 3);
    const int tix = bid % gridDim.x;
    const int niy = bid / gridDim.x;

    const int e = tE[tix];
    if (e < 0) return;

    __shared__ unsigned short smem[2 * HALF];

    const int tid = threadIdx.x;
    const int lane = tid & 63;
    const int quad = lane >> 4;
    const int l15 = lane & 15;
    const int wid = tid >> 6;
    const int wrr = wid >> 2;
    const int wcc = wid & 3;

    const long row0 = tR[tix];
    const long n0 = (long)niy * BN;
    const unsigned short* Ab = A + row0 * K;
    const unsigned short* Bb = W + ((long)e * N + n0) * K;

    const unsigned short* aS[4];
    int aD[4];
#pragma unroll
    for (int i = 0; i < 4; ++i) {
        const int c = i * 512 + tid;
        const int r = c >> 3, s = c & 7;
        aS[i] = Ab + (long)r * K + (s ^ (r & 7)) * 8;
        aD[i] = c * 8;
    }
    const unsigned short* bS[NB];
    int bD[NB];
#pragma unroll
    for (int i = 0; i < NB; ++i) {
        const int c = i * 512 + tid;
        const int rho = c >> 3, s = c & 7;
        const int rl = rho & (BN / 2 - 1);
        const int r = (rl & (HB - 1)) + ((rl >> LOG2HB) << (LOG2HB + 1)) +
                      ((rho >= BN / 2) ? HB : 0);
        bS[i] = Bb + (long)r * K + (s ^ (rho & 7)) * 8;
        bD[i] = c * 8;
    }

    auto stgA = [&](int buf, int t, int g) {
        unsigned short* dst = smem + buf * HALF;
        gload_lds16(aS[g] + (long)t * BK, dst + aD[g]);
        gload_lds16(aS[g + 2] + (long)t * BK, dst + aD[g + 2]);
    };
    auto stgB = [&](int buf, int t, int g) {
        unsigned short* dst = smem + buf * HALF + AHALF;
#pragma unroll
        for (int j = 0; j < NB2; ++j)
            gload_lds16(bS[g * NB2 + j] + (long)t * BK, dst + bD[g * NB2 + j]);
    };
    auto rdA = [&](const unsigned short* Ac, int mi, int ks) -> short8 {
        const int row = wrr * 128 + mi * 16 + l15;
        return *(const short8*)(Ac + row * BK + ((ks * 4 + quad) ^ (row & 7)) * 8);
    };
    auto rdB = [&](const unsigned short* Bc, int ni, int ks) -> short8 {
        int rho;
        if constexpr (BN == 256)
            rho = (ni & 1) * 16 + l15 + wcc * 32 + ((ni & 2) ? 128 : 0);
        else
            rho = l15 + wcc * 16 + ni * 64;
        return *(const short8*)(Bc + rho * BK + ((ks * 4 + quad) ^ (rho & 7)) * 8);
    };

#define RD_A(AF, AC, HM)                                                \
    _Pragma("unroll") for (int i_ = 0; i_ < 4; ++i_)                    \
    _Pragma("unroll") for (int k_ = 0; k_ < 2; ++k_)                    \
        AF[i_][k_] = rdA(AC, (HM) * 4 + i_, k_);
#define RD_B(BF, BC, HN)                                                \
    _Pragma("unroll") for (int j_ = 0; j_ < NREP2; ++j_)                \
    _Pragma("unroll") for (int k_ = 0; k_ < 2; ++k_)                    \
        BF[j_][k_] = rdB(BC, (HN) * NREP2 + j_, k_);
#define MMA_Q(AF, BF, HM, HN)                                           \
    _Pragma("unroll") for (int i_ = 0; i_ < 4; ++i_)                    \
    _Pragma("unroll") for (int j_ = 0; j_ < NREP2; ++j_)                \
    _Pragma("unroll") for (int k_ = 0; k_ < 2; ++k_)                    \
        acc[(HM) * 4 + i_][(HN) * NREP2 + j_] =                         \
            __builtin_amdgcn_mfma_f32_16x16x32_bf16(                    \
                AF[i_][k_], BF[j_][k_],                                 \
                acc[(HM) * 4 + i_][(HN) * NREP2 + j_], 0, 0, 0);

    f32x4 acc[8][NREP];
#pragma unroll
    for (int i = 0; i < 8; ++i)
#pragma unroll
        for (int j = 0; j < NREP; ++j) acc[i][j] = (f32x4){0.f, 0.f, 0.f, 0.f};

    stgA(0, 0, 0); stgB(0, 0, 0); stgA(0, 0, 1); stgB(0, 0, 1);
    VMC(VB);
    BARM;

#pragma unroll 1
    for (int t = 0; t < NT - 1; ++t) {
        const int cur = t & 1;
        const int nb = cur ^ 1;
        const unsigned short* Ac = smem + cur * HALF;
        const unsigned short* Bc = Ac + AHALF;
        short8 af0[4][2], af1[4][2], bf0[NREP2][2], bf1[NREP2][2];
        RD_A(af0, Ac, 0); RD_B(bf0, Bc, 0);
        stgA(nb, t + 1, 0);
        BARM; LGKM0;
        PRIO1; MMA_Q(af0, bf0, 0, 0); PRIO0;
        VMC(VB); BARM;
        RD_A(af1, Ac, 1);
        stgB(nb, t + 1, 0);
        BARM; LGKM0;
        PRIO1; MMA_Q(af1, bf0, 1, 0); PRIO0;
        VMC(VB); BARM;
        RD_B(bf1, Bc, 1);
        stgA(nb, t + 1, 1);
        BARM; LGKM0;
        PRIO1; MMA_Q(af1, bf1, 1, 1); PRIO0;
        BARM;
        stgB(nb, t + 1, 1);
        BARM;
        PRIO1; MMA_Q(af0, bf1, 0, 1); PRIO0;
        VMC(VB); BARM;
    }

    {   // peeled last tile
        const int cur = (NT - 1) & 1;
        const unsigned short* Ac = smem + cur * HALF;
        const unsigned short* Bc = Ac + AHALF;
        short8 af0[4][2], af1[4][2], bf0[NREP2][2], bf1[NREP2][2];
        RD_A(af0, Ac, 0); RD_B(bf0, Bc, 0);
        BARM; LGKM0;
        PRIO1; MMA_Q(af0, bf0, 0, 0); PRIO0;
        VMC(NB2); BARM;
        RD_A(af1, Ac, 1);
        BARM; LGKM0;
        PRIO1; MMA_Q(af1, bf0, 1, 0); PRIO0;
        VMC(0); BARM;
        RD_B(bf1, Bc, 1);
        BARM; LGKM0;
        PRIO1; MMA_Q(af1, bf1, 1, 1); PRIO0;
        PRIO1; MMA_Q(af0, bf1, 0, 1); PRIO0;
    }

#pragma unroll
    for (int mi = 0; mi < 8; ++mi) {
        const long grow0 = row0 + wrr * 128 + mi * 16 + quad * 4;
#pragma unroll
        for (int ni = 0; ni < NREP; ++ni) {
            const long col = n0 + wcc * (BN / 4) + ni * 16 + l15;
            const float bcol = bias[(long)e * N + col];
#pragma unroll
            for (int r = 0; r < 4; ++r) {
                float v = acc[mi][ni][r] + bcol;
                if constexpr (EPI == 0) v = gelu_fast(v);
                Hout[(grow0 + r) * N + col] = f2bf(v);
            }
        }
    }
#undef RD_A
#undef RD_B
#undef MMA_Q
}

// ------------------------------------------------------------- FC2 GEMM
// BM=256, BN=128, BK=64, 8 waves (2x4), double-buffered LDS (96 KB).
// TWO fat phases per K-tile (16 MFMA each): p0 reads A-h0 + all B, stages
// G0(t+1)={A-h0,B} (4 loads), ends VMC(4); p1 reads A-h1, stages G1(t+1)=
// {A-h1} (2 loads), ends VMC(2). vmcnt never 0 in the main loop.
template <int N, int K>
__global__ __launch_bounds__(512, 2) void gemm2p(
    const unsigned short* __restrict__ A,
    const unsigned short* __restrict__ W,
    const int* __restrict__ tE,
    const int* __restrict__ tR,
    unsigned short* __restrict__ Hout,
    const float* __restrict__ bias) {
    constexpr int BM = 256, BN = 128, BK = 64, NT = K / BK;
    constexpr int AHALF = BM * BK;
    constexpr int HALF = (BM + BN) * BK;

    const int nwg = gridDim.x * gridDim.y;
    int bid = blockIdx.y * gridDim.x + blockIdx.x;
    bid = (bid & 7) * (nwg >> 3) + (bid >> 3);
    const int tix = bid % gridDim.x;
    const int niy = bid / gridDim.x;

    const int e = tE[tix];
    if (e < 0) return;

    __shared__ unsigned short smem[2 * HALF];  // 96 KB

    const int tid = threadIdx.x;
    const int lane = tid & 63;
    const int quad = lane >> 4;
    const int l15 = lane & 15;
    const int wid = tid >> 6;
    const int wrr = wid >> 2;
    const int wcc = wid & 3;

    const long row0 = tR[tix];
    const long n0 = (long)niy * BN;
    const unsigned short* Ab = A + row0 * K;
    const unsigned short* Bb = W + ((long)e * N + n0) * K;

    const unsigned short* aS[4];
    int aD[4];
#pragma unroll
    for (int i = 0; i < 4; ++i) {
        const int c = i * 512 + tid;
        const int r = c >> 3, s = c & 7;
        aS[i] = Ab + (long)r * K + (s ^ (r & 7)) * 8;
        aD[i] = c * 8;
    }
    const unsigned short* bS[2];
    int bD[2];
#pragma unroll
    for (int i = 0; i < 2; ++i) {
        const int c = i * 512 + tid;
        const int r = c >> 3, s = c & 7;   // identity B rows (0..127)
        bS[i] = Bb + (long)r * K + (s ^ (r & 7)) * 8;
        bD[i] = c * 8;
    }

    auto stgA = [&](int buf, int t, int g) {
        unsigned short* dst = smem + buf * HALF;
        gload_lds16(aS[g] + (long)t * BK, dst + aD[g]);
        gload_lds16(aS[g + 2] + (long)t * BK, dst + aD[g + 2]);
    };
    auto stgB = [&](int buf, int t) {
        unsigned short* dst = smem + buf * HALF + AHALF;
        gload_lds16(bS[0] + (long)t * BK, dst + bD[0]);
        gload_lds16(bS[1] + (long)t * BK, dst + bD[1]);
    };
    auto rdA = [&](const unsigned short* Ac, int mi, int ks) -> short8 {
        const int row = wrr * 128 + mi * 16 + l15;
        return *(const short8*)(Ac + row * BK + ((ks * 4 + quad) ^ (row & 7)) * 8);
    };
    auto rdB = [&](const unsigned short* Bc, int ni, int ks) -> short8 {
        const int rho = wcc * 32 + ni * 16 + l15;
        return *(const short8*)(Bc + rho * BK + ((ks * 4 + quad) ^ (rho & 7)) * 8);
    };

    f32x4 acc[8][2];
#pragma unroll
    for (int i = 0; i < 8; ++i)
#pragma unroll
        for (int j = 0; j < 2; ++j) acc[i][j] = (f32x4){0.f, 0.f, 0.f, 0.f};

    // prologue: G0(0)=A-h0+B (4), G1(0)=A-h1 (2)
    stgA(0, 0, 0); stgB(0, 0); stgA(0, 0, 1);
    VMC(2);   // G0 landed; G1 in flight
    BARM;

#pragma unroll 1
    for (int t = 0; t < NT - 1; ++t) {
        const int cur = t & 1, nb = cur ^ 1;
        const unsigned short* Ac = smem + cur * HALF;
        const unsigned short* Bc = Ac + AHALF;
        short8 af[4][2], bf[2][2];
        // phase 0: hm0 x all-n
#pragma unroll
        for (int i = 0; i < 4; ++i)
#pragma unroll
            for (int k = 0; k < 2; ++k) af[i][k] = rdA(Ac, i, k);
#pragma unroll
        for (int j = 0; j < 2; ++j)
#pragma unroll
            for (int k = 0; k < 2; ++k) bf[j][k] = rdB(Bc, j, k);
        stgA(nb, t + 1, 0); stgB(nb, t + 1);   // G0(t+1): 4 loads
        BARM; LGKM0;
        PRIO1;
#pragma unroll
        for (int i = 0; i < 4; ++i)
#pragma unroll
            for (int j = 0; j < 2; ++j)
#pragma unroll
                for (int k = 0; k < 2; ++k)
                    acc[i][j] = __builtin_amdgcn_mfma_f32_16x16x32_bf16(
                        af[i][k], bf[j][k], acc[i][j], 0, 0, 0);
        PRIO0;
        VMC(4); BARM;   // G1(t) landed; G0(t+1) stays out
        // phase 1: hm1 x all-n
#pragma unroll
        for (int i = 0; i < 4; ++i)
#pragma unroll
            for (int k = 0; k < 2; ++k) af[i][k] = rdA(Ac, 4 + i, k);
        stgA(nb, t + 1, 1);                    // G1(t+1): 2 loads
        BARM; LGKM0;
        PRIO1;
#pragma unroll
        for (int i = 0; i < 4; ++i)
#pragma unroll
            for (int j = 0; j < 2; ++j)
#pragma unroll
                for (int k = 0; k < 2; ++k)
                    acc[4 + i][j] = __builtin_amdgcn_mfma_f32_16x16x32_bf16(
                        af[i][k], bf[j][k], acc[4 + i][j], 0, 0, 0);
        PRIO0;
        VMC(2); BARM;   // G0(t+1) landed; G1(t+1) stays out
    }

    {   // peeled last tile
        const int cur = (NT - 1) & 1;
        const unsigned short* Ac = smem + cur * HALF;
        const unsigned short* Bc = Ac + AHALF;
        short8 af[4][2], bf[2][2];
#pragma unroll
        for (int i = 0; i < 4; ++i)
#pragma unroll
            for (int k = 0; k < 2; ++k) af[i][k] = rdA(Ac, i, k);
#pragma unroll
        for (int j = 0; j < 2; ++j)
#pragma unroll
            for (int k = 0; k < 2; ++k) bf[j][k] = rdB(Bc, j, k);
        BARM; LGKM0;
        PRIO1;
#pragma unroll
        for (int i = 0; i < 4; ++i)
#pragma unroll
            for (int j = 0; j < 2; ++j)
#pragma unroll
                for (int k = 0; k < 2; ++k)
                    acc[i][j] = __builtin_amdgcn_mfma_f32_16x16x32_bf16(
                        af[i][k], bf[j][k], acc[i][j], 0, 0, 0);
        PRIO0;
        VMC(0); BARM;   // G1(NT-1) landed
#pragma unroll
        for (int i = 0; i < 4; ++i)
#pragma unroll
            for (int k = 0; k < 2; ++k) af[i][k] = rdA(Ac, 4 + i, k);
        LGKM0;
        PRIO1;
#pragma unroll
        for (int i = 0; i < 4; ++i)
#pragma unroll
            for (int j = 0; j < 2; ++j)
#pragma unroll
                for (int k = 0; k < 2; ++k)
                    acc[4 + i][j] = __builtin_amdgcn_mfma_f32_16x16x32_bf16(
                        af[i][k], bf[j][k], acc[4 + i][j], 0, 0, 0);
        PRIO0;
    }

    // epilogue: no activation (combine applies weights)
#pragma unroll
    for (int mi = 0; mi < 8; ++mi) {
        const long grow0 = row0 + wrr * 128 + mi * 16 + quad * 4;
#pragma unroll
        for (int ni = 0; ni < 2; ++ni) {
            const long col = n0 + wcc * 32 + ni * 16 + l15;
            const float bcol = bias[(long)e * N + col];
#pragma unroll
            for (int r = 0; r < 4; ++r) {
                const float v = acc[mi][ni][r] + bcol;
                Hout[(grow0 + r) * N + col] = f2bf(v);
            }
        }
    }
}

// ------------------------------------------------------------- combine
// out[t][:] = w0 * Y[pos0][:] + w1 * Y[pos1][:]   (Y bf16, fp32 accumulate)
__global__ __launch_bounds__(256) void combine_kernel(const unsigned short* __restrict__ Y,
                                                      const int* __restrict__ posOf,
                                                      const float* __restrict__ tokW,
                                                      float* __restrict__ out) {
    const int t = blockIdx.x;
    const int p0 = posOf[t * 2];
    const int p1 = posOf[t * 2 + 1];
    const float w0 = tokW[t * 2];
    const float w1 = tokW[t * 2 + 1];
    const ushort4 a = ((const ushort4*)(Y + (long)p0 * HD))[threadIdx.x];
    const ushort4 b = ((const ushort4*)(Y + (long)p1 * HD))[threadIdx.x];
    float4 o;
    o.x = w0 * bf2f(a.x) + w1 * bf2f(b.x);
    o.y = w0 * bf2f(a.y) + w1 * bf2f(b.y);
    o.z = w0 * bf2f(a.z) + w1 * bf2f(b.z);
    o.w = w0 * bf2f(a.w) + w1 * bf2f(b.w);
    ((float4*)(out + (long)t * HD))[threadIdx.x] = o;
}

// ------------------------------------------------------------- launch
extern "C" void kernel_launch(void* const* d_in, const int* in_sizes, int n_in,
                              void* d_out, int out_size, void* d_ws, size_t ws_size,
                              hipStream_t stream) {
    const float* x  = (const float*)d_in[0];   // [4,2048,1024]
    const float* wr = (const float*)d_in[1];   // [8,1024]
    const float* w1 = (const float*)d_in[2];   // [8,4096,1024]
    const float* b1 = (const float*)d_in[3];   // [8,4096]
    const float* w2 = (const float*)d_in[4];   // [8,1024,4096]
    const float* b2 = (const float*)d_in[5];   // [8,1024]
    float* out = (float*)d_out;                // [4,2048,1024] fp32

    const size_t WBYTES = (size_t)NE * DFF * HD * 2;  // 67.1 MB per weight
    const bool full = ws_size >= (size_t)326 * 1024 * 1024;

    char* p = (char*)d_ws;
    auto alloc = [&](size_t bytes) {
        char* r = p;
        p += (bytes + 255) & ~(size_t)255;
        return r;
    };
    unsigned short* Xg  = (unsigned short*)alloc((size_t)ROWCAP * HD * 2);   // 37.7 MB
    unsigned short* H1g = (unsigned short*)alloc((size_t)ROWCAP * DFF * 2);  // 151 MB
    unsigned short* Wb1 = (unsigned short*)alloc(WBYTES);                    // 67.1 MB
    unsigned short* Wb2 = full ? (unsigned short*)alloc(WBYTES) : Wb1;
    int*   rowTok  = (int*)alloc((size_t)ROWCAP * 4);
    int*   posOf   = (int*)alloc((size_t)TT * 2 * 4);
    int*   tokE    = (int*)alloc((size_t)TT * 2 * 4);
    float* tokW    = (float*)alloc((size_t)TT * 2 * 4);
    int*   counts  = (int*)alloc(64);
    int*   cursor  = (int*)alloc(64);
    int*   tEp     = (int*)alloc(MAXT * 4);
    int*   tRp     = (int*)alloc(MAXT * 4);

    // Yg (FC2 per-row bf16 output) reuses the Xg slot (Xg dead after FC1).
    unsigned short* Yg = Xg;

    // one cooperative prep dispatch: cvt + router + setup + scatter + gather
    int doW2 = full ? 1 : 0;
    void* args[] = {(void*)&x, (void*)&wr, (void*)&w1, (void*)&w2,
                    (void*)&Wb1, (void*)&Wb2, (void*)&tokE, (void*)&tokW,
                    (void*)&counts, (void*)&cursor, (void*)&tEp, (void*)&tRp,
                    (void*)&rowTok, (void*)&posOf, (void*)&Xg, (void*)&doW2};
    hipLaunchCooperativeKernel((void*)prep_kernel, dim3(512), dim3(256),
                               args, 0, stream);

    // FC1: H1g = gelu(Xg @ w1[e]^T + b1[e]);  256x256 tiles, grid 72x16
    gemm4p<0, DFF, HD, 256><<<dim3(MAXT, DFF / 256), dim3(512), 0, stream>>>(
        Xg, Wb1, tEp, tRp, H1g, b1);

    // FC2: Yg = H1g @ w2[e]^T + b2[e];  256x128 tiles, 2 fat phases, grid 72x8
    if (!full)
        cvt_w_kernel<<<dim3(4096), dim3(256), 0, stream>>>(
            w2, Wb1, (long)NE * DFF * HD / 4);
    gemm2p<HD, DFF><<<dim3(MAXT, HD / 128), dim3(512), 0, stream>>>(
        H1g, Wb2, tEp, tRp, Yg, b2);

    // combine: out[t] = w0 * Yg[pos0(t)] + w1 * Yg[pos1(t)]
    combine_kernel<<<dim3(TT), dim3(256), 0, stream>>>(Yg, posOf, tokW, out);
}